// Round 3
// baseline (205.439 us; speedup 1.0000x reference)
//
#include <hip/hip_runtime.h>
#include <math.h>

#define NPTS 300000
#define K 64
#define P 32
#define DETC 1e-16f
// ws floats: [0,64) N_k | [64,128) S_k | [128,2176) M[d][k] | [2176] int counter
#define WS_FLOATS (K + K + K * P)

#define NBLOCKS 1024
#define NTHREADS 256
#define NWAVES (NBLOCKS * (NTHREADS / 64))            // 4096
#define CHUNK ((NPTS + NWAVES - 1) / NWAVES)          // 74

// DPP add helper (bound_ctrl=1 -> out-of-range lanes contribute 0)
#define DPP_ADD(v, ctrl)                                                     \
    v += __int_as_float(__builtin_amdgcn_update_dpp(                         \
        0, __float_as_int(v), (ctrl), 0xF, 0xF, true))

__device__ __forceinline__ float rl_dyn(float x, int lane) {
    return __int_as_float(__builtin_amdgcn_readlane(__float_as_int(x), lane));
}

// full wave-64 sum; returns total (scalar) via lane 63
__device__ __forceinline__ float wave_sum64(float w) {
    float v = w;
    DPP_ADD(v, 0xB1);    // quad_perm xor1
    DPP_ADD(v, 0x4E);    // quad_perm xor2
    DPP_ADD(v, 0x128);   // row_ror:8
    DPP_ADD(v, 0x124);   // row_ror:4   -> every lane = its 16-row sum
    DPP_ADD(v, 0x142);   // row_bcast15 -> lane63 = R3+R2, lane31 = R1+R0
    DPP_ADD(v, 0x143);   // row_bcast31 -> lane63 = total
    return rl_dyn(v, 63);
}

// uniform row load -> SGPRs (pointer is wave-uniform)
__device__ __forceinline__ void loadrow(float r[P], const float* __restrict__ q) {
#pragma unroll
    for (int d = 0; d < P; ++d) r[d] = q[d];
}

__device__ __forceinline__ void point_step(
    int i, const float r[P], float u_s, float b_s,
    const float muk[P], float icov, float hicov, float Ak,
    float* __restrict__ gamma_out,
    float& accN, float& accS, float accM[P], int lane)
{
    float dot = 0.f;
#pragma unroll
    for (int d = 0; d < P; ++d) dot = fmaf(r[d], muk[d], dot);
    const float t = fmaf(-hicov, u_s, b_s) - Ak;       // 16lcp - 0.5*icov*u - Ak
    const float w = __expf(fmaf(icov, dot, t));
    const float s = wave_sum64(w);
    const float g = fmaf(w, __builtin_amdgcn_rcpf(s), DETC);
    gamma_out[(size_t)i * K + lane] = g;               // coalesced 256B
    accN += g;
    accS = fmaf(g, u_s, accS);
#pragma unroll
    for (int d = 0; d < P; ++d) accM[d] = fmaf(g, r[d], accM[d]);
}

__global__ __launch_bounds__(NTHREADS, 4) void em_pass(
    const float* __restrict__ mu_phi,
    const float* __restrict__ log_cov_phi,
    const float* __restrict__ pi_k,
    const float* __restrict__ mu_k,
    const float* __restrict__ log_cov_k,
    float* __restrict__ gamma_out,
    float* __restrict__ out_tail,   // pi_new | mu_new | log_cov_new
    float* __restrict__ ws)
{
    const int lane = threadIdx.x & 63;                 // = cluster index
    const int wave = threadIdx.x >> 6;
    const int gw = __builtin_amdgcn_readfirstlane(blockIdx.x * (NTHREADS / 64) + wave);

    // ---- per-lane cluster constants ----
    float muk[P];
#pragma unroll
    for (int d = 0; d < P; ++d) muk[d] = mu_k[lane * P + d];
    const float lck  = log_cov_k[lane];
    const float icov = __expf(-lck);
    const float pik  = pi_k[lane];
    float n2k = 0.f;
#pragma unroll
    for (int d = 0; d < P; ++d) n2k = fmaf(muk[d], muk[d], n2k);
    // KL = Ak - 16*lcp + 0.5*icov*u - icov*dot ; w = pik*exp(-KL)
    const float Ak    = 0.5f * (32.f * lck - 32.f + icov * n2k) - __logf(pik);
    const float hicov = 0.5f * icov;

    float accN = 0.f, accS = 0.f;
    float accM[P];
#pragma unroll
    for (int d = 0; d < P; ++d) accM[d] = 0.f;

    const int start = gw * CHUNK;
    const int end0  = (start + CHUNK < NPTS) ? (start + CHUNK) : NPTS;

    for (int gb = start; gb < end0; gb += 64) {
        const int cnt = (end0 - gb < 64) ? (end0 - gb) : 64;

        // ---- divergent u-phase: lane = point; 8 independent float4 loads ----
        float u_v = 0.f, b_v = 0.f;
        {
            const int ip = gb + lane;
            if (lane < cnt) {
                const float4* r4 = reinterpret_cast<const float4*>(mu_phi + (size_t)ip * P);
                float4 a0 = r4[0], a1 = r4[1], a2 = r4[2], a3 = r4[3];
                float4 a4 = r4[4], a5 = r4[5], a6 = r4[6], a7 = r4[7];
                float n2 = 0.f;
#define N2ACC(q) n2 = fmaf(q.x,q.x,n2); n2 = fmaf(q.y,q.y,n2); \
                 n2 = fmaf(q.z,q.z,n2); n2 = fmaf(q.w,q.w,n2)
                N2ACC(a0); N2ACC(a1); N2ACC(a2); N2ACC(a3);
                N2ACC(a4); N2ACC(a5); N2ACC(a6); N2ACC(a7);
#undef N2ACC
                const float lcp = log_cov_phi[ip];
                u_v = fmaf(32.f, __expf(lcp), n2);     // P*e^lcp + ||phi||^2
                b_v = 16.f * lcp;
            }
        }

        // ---- per-point phase: lane = cluster; rows double-buffered in SGPRs ----
        float r0[P], r1[P];
        loadrow(r0, mu_phi + (size_t)gb * P);
        for (int p = 0; p < cnt; p += 2) {
            {   // prefetch row p+1 while computing p
                const int inx = (gb + p + 1 < NPTS) ? (gb + p + 1) : (NPTS - 1);
                loadrow(r1, mu_phi + (size_t)inx * P);
            }
            point_step(gb + p, r0, rl_dyn(u_v, p), rl_dyn(b_v, p),
                       muk, icov, hicov, Ak, gamma_out, accN, accS, accM, lane);
            {   // prefetch row p+2 while computing p+1
                const int inx = (gb + p + 2 < NPTS) ? (gb + p + 2) : (NPTS - 1);
                loadrow(r0, mu_phi + (size_t)inx * P);
            }
            if (p + 1 < cnt)
                point_step(gb + p + 1, r1, rl_dyn(u_v, p + 1), rl_dyn(b_v, p + 1),
                           muk, icov, hicov, Ak, gamma_out, accN, accS, accM, lane);
        }
    }

    // ---- block combine in LDS, then one set of global atomics ----
    __shared__ float lN[K], lS[K], lM[K * P];
    for (int idx = threadIdx.x; idx < K; idx += NTHREADS) { lN[idx] = 0.f; lS[idx] = 0.f; }
    for (int idx = threadIdx.x; idx < K * P; idx += NTHREADS) lM[idx] = 0.f;
    __syncthreads();

    atomicAdd(&lN[lane], accN);
    atomicAdd(&lS[lane], accS);
#pragma unroll
    for (int d = 0; d < P; ++d) atomicAdd(&lM[d * K + lane], accM[d]);
    __syncthreads();

    for (int idx = threadIdx.x; idx < K; idx += NTHREADS) {
        atomicAdd(&ws[idx], lN[idx]);
        atomicAdd(&ws[K + idx], lS[idx]);
    }
    for (int idx = threadIdx.x; idx < K * P; idx += NTHREADS)
        atomicAdd(&ws[2 * K + idx], lM[idx]);
    __syncthreads();

    // ---- decoupled finalize: last block computes the small outputs ----
    __shared__ int lastf;
    if (threadIdx.x == 0) {
        __threadfence();
        const int c = atomicAdd((int*)(ws + WS_FLOATS), 1);
        lastf = (c == NBLOCKS - 1);
    }
    __syncthreads();
    if (lastf) {
        __threadfence();
        const int k = threadIdx.x;
        if (k < K) {
            const float Nk = __hip_atomic_load(&ws[k],     __ATOMIC_RELAXED, __HIP_MEMORY_SCOPE_AGENT);
            const float S  = __hip_atomic_load(&ws[K + k], __ATOMIC_RELAXED, __HIP_MEMORY_SCOPE_AGENT);
            float* pi_new      = out_tail;
            float* mu_new      = out_tail + K;
            float* log_cov_new = out_tail + K + K * P;

            pi_new[k] = Nk / (float)NPTS;
            const float invN = 1.f / Nk;
            float m2 = 0.f;
#pragma unroll
            for (int d = 0; d < P; ++d) {
                const float md = __hip_atomic_load(&ws[2 * K + d * K + k],
                                                   __ATOMIC_RELAXED, __HIP_MEMORY_SCOPE_AGENT) * invN;
                mu_new[k * P + d] = md;
                m2 = fmaf(md, md, m2);
            }
            const float cov = (S - Nk * m2) / (32.f * Nk);
            log_cov_new[k] = logf(cov);
        }
    }
}

extern "C" void kernel_launch(void* const* d_in, const int* in_sizes, int n_in,
                              void* d_out, int out_size, void* d_ws, size_t ws_size,
                              hipStream_t stream)
{
    const float* mu_phi      = (const float*)d_in[0];
    const float* log_cov_phi = (const float*)d_in[1];
    const float* pi_k        = (const float*)d_in[2];
    const float* mu_k        = (const float*)d_in[3];
    const float* log_cov_k   = (const float*)d_in[4];
    float* out = (float*)d_out;
    float* ws  = (float*)d_ws;

    hipMemsetAsync(ws, 0, (WS_FLOATS + 1) * sizeof(float), stream);
    em_pass<<<NBLOCKS, NTHREADS, 0, stream>>>(mu_phi, log_cov_phi, pi_k, mu_k,
                                              log_cov_k, out,
                                              out + (size_t)NPTS * K, ws);
}